// Round 6
// baseline (1062.729 us; speedup 1.0000x reference)
//
#include <hip/hip_runtime.h>
#include <math.h>

typedef __attribute__((ext_vector_type(8))) short short8;
typedef __attribute__((ext_vector_type(16))) float floatx16;

__device__ __forceinline__ float silu_f(float v) { return v / (1.0f + expf(-v)); }
__device__ __forceinline__ float bf2f(unsigned short u) {
    unsigned int x = ((unsigned int)u) << 16;
    return __uint_as_float(x);
}
__device__ __forceinline__ unsigned short f2bf(float f) {
    unsigned int u = __float_as_uint(f);
    u += 0x7FFFu + ((u >> 16) & 1u);
    return (unsigned short)(u >> 16);
}

struct BSlots { const unsigned short* p[4]; };

// ---------------- bf16 MFMA GEMM (1x1 conv), double-buffered LDS, ONE barrier
// per 32-K tile. out[(z*OC+m)*4096+n] = EPI( sum_k A[m][k]*B[k][n] + bias[m] ).
// Block tile 128m x 128n, 4 waves of 64m x 64n. A,B rows pitch 20 dwords with
// chunk-XOR swizzle (chunk = 4 dwords) -> b128 LDS ops at bank minimum.
// Dual-branch: if Ahp2 != null and m0>=512 use branch-2 tensors (merged cv1/cv2).
// EPI: 0 = SiLU -> bf16; 1 = gate-mult by Y2b -> bf16; 2 = SiLU -> f32
template <int EPI>
__global__ __launch_bounds__(256, 3)
void gemm_mfma(const unsigned short* __restrict__ Ahp,
               const unsigned short* __restrict__ Ahp2, int ldK,
               BSlots bs, BSlots bs2, long bstride,
               const float* __restrict__ bias, const float* __restrict__ bias2,
               void* __restrict__ outv, int OC,
               const unsigned short* __restrict__ gate, int b0, int K)
{
    __shared__ __align__(16) unsigned short As[2][128 * 40];
    __shared__ __align__(16) unsigned int   Bsm[2][128 * 20];

    const int t  = threadIdx.x;
    const int z  = blockIdx.z;
    const int m0 = blockIdx.y * 128;
    const int n0 = blockIdx.x * 128;

    int mA = m0;
    if (Ahp2 != nullptr && m0 >= 512) {
        Ahp = Ahp2; bias = bias2; bs = bs2; mA = m0 - 512;
    }

    // staging ids
    const int am = t >> 1, ahf = t & 1;   // A: row 0..127, k-half (16 shorts)
    const int n2 = t & 63, kg = t >> 6;   // B: n-pair, k-octet group
    const int bcol = n0 + n2 * 2;
    // compute ids
    const int w = t >> 6, lane = t & 63;
    const int wm = (w & 1) * 64, wn = (w >> 1) * 64;
    const int lm = lane & 31, q = lane >> 5;

    floatx16 acc[2][2];
#pragma unroll
    for (int i = 0; i < 2; ++i)
#pragma unroll
        for (int j = 0; j < 2; ++j)
#pragma unroll
            for (int r = 0; r < 16; ++r) acc[i][j][r] = 0.0f;

    const unsigned short* Ap = Ahp + (size_t)(mA + am) * ldK + ahf * 16;

    uint4 asg0[2], asg1[2];
    unsigned int bsg0[8], bsg1[8];

    auto LOADA = [&](uint4* d, int k) {
        d[0] = *(const uint4*)(Ap + k);
        d[1] = *(const uint4*)(Ap + k + 8);
    };
    auto LOADB = [&](unsigned int* d, int k) {
        const unsigned short* Bp = bs.p[k >> 8] + (size_t)z * bstride
                                 + (size_t)((k & 255) + kg * 8) * 4096 + bcol;
#pragma unroll
        for (int r = 0; r < 8; ++r) d[r] = *(const unsigned int*)(Bp + (size_t)r * 4096);
    };
    auto STOREA = [&](int p, uint4* s) {
        int c0 = (2 * ahf) ^ (am & 3);
        int c1 = (2 * ahf + 1) ^ (am & 3);
        *(uint4*)&As[p][am * 40 + c0 * 8] = s[0];
        *(uint4*)&As[p][am * 40 + c1 * 8] = s[1];
    };
    auto STOREB = [&](int p, unsigned int* s) {
        int r0 = n2 * 2, r1 = n2 * 2 + 1;
        uint4 v;
        v.x = __builtin_amdgcn_perm(s[1], s[0], 0x05040100u);
        v.y = __builtin_amdgcn_perm(s[3], s[2], 0x05040100u);
        v.z = __builtin_amdgcn_perm(s[5], s[4], 0x05040100u);
        v.w = __builtin_amdgcn_perm(s[7], s[6], 0x05040100u);
        *(uint4*)&Bsm[p][r0 * 20 + ((kg ^ (r0 & 3)) * 4)] = v;
        v.x = __builtin_amdgcn_perm(s[1], s[0], 0x07060302u);
        v.y = __builtin_amdgcn_perm(s[3], s[2], 0x07060302u);
        v.z = __builtin_amdgcn_perm(s[5], s[4], 0x07060302u);
        v.w = __builtin_amdgcn_perm(s[7], s[6], 0x07060302u);
        *(uint4*)&Bsm[p][r1 * 20 + ((kg ^ (r1 & 3)) * 4)] = v;
    };
    auto COMPUTE = [&](int p) {
#pragma unroll
        for (int s = 0; s < 2; ++s) {
            union { short8 v; uint4 u; } af[2], bf[2];
            const int ca = (2 * s + q) ^ (lm & 3);
            af[0].u = *(const uint4*)&As[p][(wm + lm) * 40 + ca * 8];
            af[1].u = *(const uint4*)&As[p][(wm + 32 + lm) * 40 + ca * 8];
            bf[0].u = *(const uint4*)&Bsm[p][(wn + lm) * 20 + ca * 4];
            bf[1].u = *(const uint4*)&Bsm[p][(wn + 32 + lm) * 20 + ca * 4];
            acc[0][0] = __builtin_amdgcn_mfma_f32_32x32x16_bf16(af[0].v, bf[0].v, acc[0][0], 0, 0, 0);
            acc[0][1] = __builtin_amdgcn_mfma_f32_32x32x16_bf16(af[0].v, bf[1].v, acc[0][1], 0, 0, 0);
            acc[1][0] = __builtin_amdgcn_mfma_f32_32x32x16_bf16(af[1].v, bf[0].v, acc[1][0], 0, 0, 0);
            acc[1][1] = __builtin_amdgcn_mfma_f32_32x32x16_bf16(af[1].v, bf[1].v, acc[1][1], 0, 0, 0);
        }
    };

    LOADA(asg0, 0); LOADB(bsg0, 0);
    for (int k0 = 0; k0 < K; k0 += 64) {
        STOREA(0, asg0); STOREB(0, bsg0);
        LOADA(asg1, k0 + 32); LOADB(bsg1, k0 + 32);
        __syncthreads();
        COMPUTE(0);
        STOREA(1, asg1); STOREB(1, bsg1);
        if (k0 + 64 < K) { LOADA(asg0, k0 + 64); LOADB(bsg0, k0 + 64); }
        __syncthreads();
        COMPUTE(1);
    }

    // ---- epilogue; C/D: col=lane&31, row=(reg&3)+8*(reg>>2)+4*(lane>>5)
#pragma unroll
    for (int i = 0; i < 2; ++i)
#pragma unroll
        for (int j = 0; j < 2; ++j)
#pragma unroll
            for (int r = 0; r < 16; ++r) {
                int row = wm + 32 * i + (r & 3) + 8 * (r >> 2) + 4 * q;
                int col = n0 + wn + 32 * j + lm;
                int mg  = m0 + row;
                size_t ob = ((size_t)z * OC + mg) * 4096 + col;
                float v = acc[i][j][r] + bias[mA + row];
                if (EPI == 0) {
                    ((unsigned short*)outv)[ob] = f2bf(silu_f(v));
                } else if (EPI == 1) {
                    float g = bf2f(gate[((size_t)(b0 + z) * 1024 + mg) * 4096 + col]);
                    ((unsigned short*)outv)[ob] = f2bf(v * g);
                } else {
                    ((float*)outv)[ob] = silu_f(v);
                }
            }
}

// ---------------- fused separable 5x5 TMaxAvg pool, bf16 io, block = one plane
__global__ __launch_bounds__(256)
void pool_tma_b(const unsigned short* __restrict__ in, unsigned short* __restrict__ out)
{
    __shared__ float xs[4096], hm[4096], hs[4096];
    const size_t base = (size_t)blockIdx.x * 4096;
    const int t = threadIdx.x;
    for (int i = t; i < 4096; i += 256) xs[i] = bf2f(in[base + i]);
    __syncthreads();
    for (int i = t; i < 4096; i += 256) {
        int x = i & 63;
        float mx = -INFINITY, sm = 0.0f;
#pragma unroll
        for (int dx = -2; dx <= 2; ++dx) {
            int xx = x + dx;
            if (0 <= xx && xx < 64) { float v = xs[i + dx]; mx = fmaxf(mx, v); sm += v; }
        }
        hm[i] = mx; hs[i] = sm;
    }
    __syncthreads();
    for (int i = t; i < 4096; i += 256) {
        int y = i >> 6;
        float mx = -INFINITY, sm = 0.0f;
#pragma unroll
        for (int dy = -2; dy <= 2; ++dy) {
            int yy = y + dy;
            if (0 <= yy && yy < 64) { mx = fmaxf(mx, hm[i + dy * 64]); sm += hs[i + dy * 64]; }
        }
        out[base + i] = f2bf(0.9f * mx + 0.1f * (sm * (1.0f / 25.0f)));
    }
}

// ---------------- fused separable 5x5 RW pool, bf16 io (global shift cancels)
__global__ __launch_bounds__(256)
void pool_rw_b(const unsigned short* __restrict__ in, unsigned short* __restrict__ out)
{
    __shared__ float xs[4096], hx[4096], he[4096];
    const size_t base = (size_t)blockIdx.x * 4096;
    const int t = threadIdx.x;
    for (int i = t; i < 4096; i += 256) xs[i] = bf2f(in[base + i]);
    __syncthreads();
    for (int i = t; i < 4096; i += 256) {
        int x = i & 63;
        float se = 0.0f, sx = 0.0f;
#pragma unroll
        for (int dx = -2; dx <= 2; ++dx) {
            int xx = x + dx;
            if (0 <= xx && xx < 64) {
                float v = xs[i + dx];
                float e = expf(v);
                se += e; sx += e * v;
            }
        }
        hx[i] = sx; he[i] = se;
    }
    __syncthreads();
    for (int i = t; i < 4096; i += 256) {
        int y = i >> 6;
        float se = 0.0f, sx = 0.0f;
#pragma unroll
        for (int dy = -2; dy <= 2; ++dy) {
            int yy = y + dy;
            if (0 <= yy && yy < 64) { sx += hx[i + dy * 64]; se += he[i + dy * 64]; }
        }
        out[base + i] = f2bf(sx / (se + 1e-6f));
    }
}

// ---------------- fused LSKA depthwise chain for a batch-QUAD, bf16 io
__global__ __launch_bounds__(256)
void lska_dw_quad(const unsigned short* __restrict__ Y2b, int b0,
                  const float* __restrict__ wh1, const float* __restrict__ bh1,
                  const float* __restrict__ wv1, const float* __restrict__ bv1,
                  const float* __restrict__ wh2, const float* __restrict__ bh2,
                  const float* __restrict__ wv2, const float* __restrict__ bv2,
                  unsigned short* __restrict__ outq)
{
    __shared__ float buf0[4096], buf1[4096];
    const int bi = blockIdx.x;
    const int zz = bi >> 10, c = bi & 1023;
    const unsigned short* src = Y2b + ((size_t)(b0 + zz) * 1024 + c) * 4096;
    unsigned short* dst = outq + (size_t)bi * 4096;
    const int t = threadIdx.x;
    for (int i = t; i < 4096; i += 256) buf0[i] = bf2f(src[i]);
    __syncthreads();
    {
        float w0 = wh1[c * 3], w1 = wh1[c * 3 + 1], w2 = wh1[c * 3 + 2], bb = bh1[c];
        for (int i = t; i < 4096; i += 256) {
            int x = i & 63;
            float a = fmaf(w1, buf0[i], bb);
            if (x >= 1)  a = fmaf(w0, buf0[i - 1], a);
            if (x <= 62) a = fmaf(w2, buf0[i + 1], a);
            buf1[i] = a;
        }
    }
    __syncthreads();
    {
        float w0 = wv1[c * 3], w1 = wv1[c * 3 + 1], w2 = wv1[c * 3 + 2], bb = bv1[c];
        for (int i = t; i < 4096; i += 256) {
            int y = i >> 6;
            float a = fmaf(w1, buf1[i], bb);
            if (y >= 1)  a = fmaf(w0, buf1[i - 64], a);
            if (y <= 62) a = fmaf(w2, buf1[i + 64], a);
            buf0[i] = a;
        }
    }
    __syncthreads();
    {
        float w0 = wh2[c * 3], w1 = wh2[c * 3 + 1], w2 = wh2[c * 3 + 2], bb = bh2[c];
        for (int i = t; i < 4096; i += 256) {
            int x = i & 63;
            float a = fmaf(w1, buf0[i], bb);
            if (x >= 2)  a = fmaf(w0, buf0[i - 2], a);
            if (x <= 61) a = fmaf(w2, buf0[i + 2], a);
            buf1[i] = a;
        }
    }
    __syncthreads();
    {
        float w0 = wv2[c * 3], w1 = wv2[c * 3 + 1], w2 = wv2[c * 3 + 2], bb = bv2[c];
        for (int i = t; i < 4096; i += 256) {
            int y = i >> 6;
            float a = fmaf(w1, buf1[i], bb);
            if (y >= 2)  a = fmaf(w0, buf1[i - 128], a);
            if (y <= 61) a = fmaf(w2, buf1[i + 128], a);
            dst[i] = f2bf(a);
        }
    }
}

// ---------------- conversions
__global__ void f2bf_vec(const float* __restrict__ in, unsigned short* __restrict__ out)
{
    size_t i = ((size_t)blockIdx.x * 256 + threadIdx.x) * 8;
    float4 v0 = *(const float4*)(in + i);
    float4 v1 = *(const float4*)(in + i + 4);
    uint2 o0, o1;
    o0.x = (unsigned)f2bf(v0.x) | ((unsigned)f2bf(v0.y) << 16);
    o0.y = (unsigned)f2bf(v0.z) | ((unsigned)f2bf(v0.w) << 16);
    o1.x = (unsigned)f2bf(v1.x) | ((unsigned)f2bf(v1.y) << 16);
    o1.y = (unsigned)f2bf(v1.z) | ((unsigned)f2bf(v1.w) << 16);
    *(uint2*)(out + i) = o0;
    *(uint2*)(out + i + 4) = o1;
}

__global__ void whi(const float* __restrict__ w, unsigned short* __restrict__ wh)
{
    int i = blockIdx.x * 256 + threadIdx.x;
    wh[i] = f2bf(w[i]);
}

extern "C" void kernel_launch(void* const* d_in, const int* in_sizes, int n_in,
                              void* d_out, int out_size, void* d_ws, size_t ws_size,
                              hipStream_t stream)
{
    const float* x       = (const float*)d_in[0];
    const float* w_sta   = (const float*)d_in[1];
    const float* b_sta   = (const float*)d_in[2];
    const float* w_cv1   = (const float*)d_in[3];
    const float* b_cv1   = (const float*)d_in[4];
    const float* w_cv2   = (const float*)d_in[5];
    const float* b_cv2   = (const float*)d_in[6];
    const float* w_cvend = (const float*)d_in[7];
    const float* b_cvend = (const float*)d_in[8];
    const float* w_dwh   = (const float*)d_in[9];
    const float* b_dwh   = (const float*)d_in[10];
    const float* w_dwv   = (const float*)d_in[11];
    const float* b_dwv   = (const float*)d_in[12];
    const float* w_ddwh  = (const float*)d_in[13];
    const float* b_ddwh  = (const float*)d_in[14];
    const float* w_ddwv  = (const float*)d_in[15];
    const float* b_ddwv  = (const float*)d_in[16];
    const float* w_c1    = (const float*)d_in[17];
    const float* b_c1    = (const float*)d_in[18];
    float* outf = (float*)d_out;
    unsigned short* Y2b = (unsigned short*)d_out;   // [8,1024,4096] bf16 = 67.1 MB

    // ws (bf16 element offsets), total 122.9 MB <= 128 MiB:
    //   xaux, t1..t3, r1..r3: 7 x 8,388,608 shorts; WT (hi-only weights) after.
    // Overlays: xb (input bf16) = t1+t2 (dead until pools); phase-4: a4q =
    // xaux+t1, gq = t2+t3 (pools dead then).
    unsigned short* WS   = (unsigned short*)d_ws;
    unsigned short* xaux = WS;
    unsigned short* t1   = WS + 8388608;
    unsigned short* t2   = WS + 16777216;
    unsigned short* t3   = WS + 25165824;
    unsigned short* r1   = WS + 33554432;
    unsigned short* r2   = WS + 41943040;
    unsigned short* r3   = WS + 50331648;
    unsigned short* WT   = WS + 58720256;
    unsigned short* xb   = t1;
    unsigned short* a4q  = WS;
    unsigned short* gq   = WS + 16777216;

    unsigned short* sta_h = WT;              // 131072
    unsigned short* cv1_h = WT + 131072;     // 524288
    unsigned short* cv2_h = WT + 655360;     // 524288
    unsigned short* c1_h  = WT + 1179648;    // 1048576
    unsigned short* cve_h = WT + 2228224;    // 524288

    dim3 blk(256);

    // 0) conversions
    f2bf_vec<<<8192, blk, 0, stream>>>(x, xb);
    whi<<<512,  blk, 0, stream>>>(w_sta,   sta_h);
    whi<<<2048, blk, 0, stream>>>(w_cv1,   cv1_h);
    whi<<<2048, blk, 0, stream>>>(w_cv2,   cv2_h);
    whi<<<4096, blk, 0, stream>>>(w_c1,    c1_h);
    whi<<<2048, blk, 0, stream>>>(w_cvend, cve_h);

    // 1) x_aux = SiLU(sta(x)) -> bf16 [8,256,4096]
    {
        BSlots s; s.p[0] = xb; s.p[1] = xb + 1048576; s.p[2] = xb; s.p[3] = xb;
        gemm_mfma<0><<<dim3(32, 2, 8), blk, 0, stream>>>(
            sta_h, nullptr, 512, s, s, 2097152L, b_sta, nullptr,
            xaux, 256, nullptr, 0, 512);
    }

    // 2) RW pool cascade -> r1,r2,r3
    pool_rw_b<<<2048, blk, 0, stream>>>(xaux, r1);
    pool_rw_b<<<2048, blk, 0, stream>>>(r1, r2);
    pool_rw_b<<<2048, blk, 0, stream>>>(r2, r3);

    // 3) TMaxAvg cascade -> t1,t2,t3 (t1 overwrites xb, which is dead)
    pool_tma_b<<<2048, blk, 0, stream>>>(xaux, t1);
    pool_tma_b<<<2048, blk, 0, stream>>>(t1, t2);
    pool_tma_b<<<2048, blk, 0, stream>>>(t2, t3);

    // 4) merged cv1+cv2 -> Y2b channels [0,512)=cv1, [512,1024)=cv2
    {
        BSlots s1; s1.p[0] = xaux; s1.p[1] = t1; s1.p[2] = t2; s1.p[3] = t3;
        BSlots s2; s2.p[0] = xaux; s2.p[1] = r1; s2.p[2] = r2; s2.p[3] = r3;
        gemm_mfma<0><<<dim3(32, 8, 8), blk, 0, stream>>>(
            cv1_h, cv2_h, 1024, s1, s2, 1048576L, b_cv1, b_cv2,
            Y2b, 1024, nullptr, 0, 1024);
    }

    // 5) per batch-quad: dw chain -> a4q ; gated c1 -> gq ; cvend -> d_out
    for (int qd = 0; qd < 2; ++qd) {
        const int b0 = 4 * qd;
        lska_dw_quad<<<4096, blk, 0, stream>>>(Y2b, b0,
                                               w_dwh, b_dwh, w_dwv, b_dwv,
                                               w_ddwh, b_ddwh, w_ddwv, b_ddwv, a4q);
        {
            BSlots s; s.p[0] = a4q; s.p[1] = a4q + 1048576;
            s.p[2] = a4q + 2097152; s.p[3] = a4q + 3145728;
            gemm_mfma<1><<<dim3(32, 8, 4), blk, 0, stream>>>(
                c1_h, nullptr, 1024, s, s, 4194304L, b_c1, nullptr,
                gq, 1024, Y2b, b0, 1024);
        }
        {
            BSlots s; s.p[0] = gq; s.p[1] = gq + 1048576;
            s.p[2] = gq + 2097152; s.p[3] = gq + 3145728;
            gemm_mfma<2><<<dim3(32, 4, 4), blk, 0, stream>>>(
                cve_h, nullptr, 1024, s, s, 4194304L, b_cvend, nullptr,
                outf + (size_t)b0 * 2097152, 512, nullptr, 0, 1024);
        }
    }
}

// Round 7
// 986.805 us; speedup vs baseline: 1.0769x; 1.0769x over previous
//
#include <hip/hip_runtime.h>
#include <math.h>

typedef __attribute__((ext_vector_type(8))) short short8;
typedef __attribute__((ext_vector_type(16))) float floatx16;

__device__ __forceinline__ float silu_f(float v) { return v / (1.0f + expf(-v)); }
__device__ __forceinline__ float bf2f(unsigned short u) {
    unsigned int x = ((unsigned int)u) << 16;
    return __uint_as_float(x);
}
__device__ __forceinline__ unsigned short f2bf(float f) {
    unsigned int u = __float_as_uint(f);
    u += 0x7FFFu + ((u >> 16) & 1u);
    return (unsigned short)(u >> 16);
}

struct BSlots { const unsigned short* p[4]; };

// ---------------- bf16 MFMA GEMM (1x1 conv), B-only LDS double buffer, ONE
// barrier per 32-K tile. A fragments are read DIRECTLY from global (weights are
// L2-resident, already in MFMA A-layout: 16B per lane). B image in LDS:
// [n][k-pair dwords], pitch 17 dwords -> frag ds_read_b128 is bank-conflict-free
// (17*lm mod 32 bijective, q adds +4 -> every bank exactly 2 lanes).
// Dual-branch: if Ahp2 != null and m0>=512 use branch-2 tensors (merged cv1/cv2).
// EPI: 0 = SiLU -> bf16; 1 = gate-mult by Y2b -> bf16; 2 = SiLU -> f32
template <int EPI>
__global__ __launch_bounds__(256, 2)
void gemm_mfma(const unsigned short* __restrict__ Ahp,
               const unsigned short* __restrict__ Ahp2, int ldK,
               BSlots bs, BSlots bs2, long bstride,
               const float* __restrict__ bias, const float* __restrict__ bias2,
               void* __restrict__ outv, int OC,
               const unsigned short* __restrict__ gate, int b0, int K)
{
    __shared__ __align__(16) unsigned int Bsm[2][128 * 17];

    const int t  = threadIdx.x;
    const int z  = blockIdx.z;
    const int m0 = blockIdx.y * 128;
    const int n0 = blockIdx.x * 128;

    int mA = m0;
    if (Ahp2 != nullptr && m0 >= 512) {
        Ahp = Ahp2; bias = bias2; bs = bs2; mA = m0 - 512;
    }

    const int w = t >> 6, lane = t & 63;
    const int wm = (w & 1) * 64, wn = (w >> 1) * 64;
    const int lm = lane & 31, q = lane >> 5;
    const int e = lane & 1;   // row-parity mix for store banking

    // perm selectors: sel1 extracts the (e ? odd-n : even-n) shorts, sel2 other
    const unsigned int selL = 0x05040100u, selH = 0x07060302u;
    const unsigned int sel1 = e ? selH : selL;
    const unsigned int sel2 = e ? selL : selH;
    // store rows: inst1 -> 2*lane+e, inst2 -> 2*lane+1-e (parity-mixed banks)
    const int sr1 = (2 * lane + e) * 17 + w * 4;
    const int sr2 = (2 * lane + 1 - e) * 17 + w * 4;

    floatx16 acc[2][2];
#pragma unroll
    for (int i = 0; i < 2; ++i)
#pragma unroll
        for (int j = 0; j < 2; ++j)
#pragma unroll
            for (int r = 0; r < 16; ++r) acc[i][j][r] = 0.0f;

    // A: direct-global fragment base (row = mA + wm + 32i + lm, 16B at k-offset)
    const unsigned short* Abase = Ahp + (size_t)(mA + lm) * ldK;
    const size_t arow0 = (size_t)wm * ldK;
    const size_t arow1 = (size_t)(wm + 32) * ldK;

    unsigned int bsg0[8], bsg1[8];

    auto LOADB = [&](unsigned int* d, int k) {
        const unsigned short* Bp = bs.p[k >> 8] + (size_t)z * bstride
                                 + (size_t)((k & 255) + 8 * w) * 4096 + n0 + 2 * lane;
#pragma unroll
        for (int r = 0; r < 8; ++r)
            d[r] = *(const unsigned int*)(Bp + (size_t)r * 4096);
    };
    auto STOREB = [&](int p, unsigned int* s) {
        uint4 v1, v2;
        v1.x = __builtin_amdgcn_perm(s[1], s[0], sel1);
        v1.y = __builtin_amdgcn_perm(s[3], s[2], sel1);
        v1.z = __builtin_amdgcn_perm(s[5], s[4], sel1);
        v1.w = __builtin_amdgcn_perm(s[7], s[6], sel1);
        v2.x = __builtin_amdgcn_perm(s[1], s[0], sel2);
        v2.y = __builtin_amdgcn_perm(s[3], s[2], sel2);
        v2.z = __builtin_amdgcn_perm(s[5], s[4], sel2);
        v2.w = __builtin_amdgcn_perm(s[7], s[6], sel2);
        *(uint4*)&Bsm[p][sr1] = v1;
        *(uint4*)&Bsm[p][sr2] = v2;
    };
    auto COMPUTE = [&](int p, int kb) {
        union { short8 v; uint4 u; } af[2][2], bf[2][2];
#pragma unroll
        for (int s = 0; s < 2; ++s) {
            const size_t ka = (size_t)(kb + s * 16 + q * 8);
            af[s][0].u = *(const uint4*)(Abase + arow0 + ka);
            af[s][1].u = *(const uint4*)(Abase + arow1 + ka);
            const int cc = (2 * s + q) * 4;
            bf[s][0].u = *(const uint4*)&Bsm[p][(wn + lm) * 17 + cc];
            bf[s][1].u = *(const uint4*)&Bsm[p][(wn + 32 + lm) * 17 + cc];
        }
#pragma unroll
        for (int s = 0; s < 2; ++s) {
            acc[0][0] = __builtin_amdgcn_mfma_f32_32x32x16_bf16(af[s][0].v, bf[s][0].v, acc[0][0], 0, 0, 0);
            acc[0][1] = __builtin_amdgcn_mfma_f32_32x32x16_bf16(af[s][0].v, bf[s][1].v, acc[0][1], 0, 0, 0);
            acc[1][0] = __builtin_amdgcn_mfma_f32_32x32x16_bf16(af[s][1].v, bf[s][0].v, acc[1][0], 0, 0, 0);
            acc[1][1] = __builtin_amdgcn_mfma_f32_32x32x16_bf16(af[s][1].v, bf[s][1].v, acc[1][1], 0, 0, 0);
        }
    };

    LOADB(bsg0, 0);
    for (int k0 = 0; k0 < K; k0 += 64) {
        STOREB(0, bsg0);
        LOADB(bsg1, k0 + 32);
        __syncthreads();
        COMPUTE(0, k0);
        STOREB(1, bsg1);
        if (k0 + 64 < K) LOADB(bsg0, k0 + 64);
        __syncthreads();
        COMPUTE(1, k0 + 32);
    }

    // ---- epilogue; C/D: col=lane&31, row=(reg&3)+8*(reg>>2)+4*(lane>>5)
#pragma unroll
    for (int i = 0; i < 2; ++i)
#pragma unroll
        for (int j = 0; j < 2; ++j)
#pragma unroll
            for (int r = 0; r < 16; ++r) {
                int row = wm + 32 * i + (r & 3) + 8 * (r >> 2) + 4 * q;
                int col = n0 + wn + 32 * j + lm;
                int mg  = m0 + row;
                size_t ob = ((size_t)z * OC + mg) * 4096 + col;
                float v = acc[i][j][r] + bias[mA + row];
                if (EPI == 0) {
                    ((unsigned short*)outv)[ob] = f2bf(silu_f(v));
                } else if (EPI == 1) {
                    float g = bf2f(gate[((size_t)(b0 + z) * 1024 + mg) * 4096 + col]);
                    ((unsigned short*)outv)[ob] = f2bf(v * g);
                } else {
                    ((float*)outv)[ob] = silu_f(v);
                }
            }
}

// ---------------- fused separable 5x5 TMaxAvg pool, bf16 io, block = one plane
__global__ __launch_bounds__(256)
void pool_tma_b(const unsigned short* __restrict__ in, unsigned short* __restrict__ out)
{
    __shared__ float xs[4096], hm[4096], hs[4096];
    const size_t base = (size_t)blockIdx.x * 4096;
    const int t = threadIdx.x;
    for (int i = t; i < 4096; i += 256) xs[i] = bf2f(in[base + i]);
    __syncthreads();
    for (int i = t; i < 4096; i += 256) {
        int x = i & 63;
        float mx = -INFINITY, sm = 0.0f;
#pragma unroll
        for (int dx = -2; dx <= 2; ++dx) {
            int xx = x + dx;
            if (0 <= xx && xx < 64) { float v = xs[i + dx]; mx = fmaxf(mx, v); sm += v; }
        }
        hm[i] = mx; hs[i] = sm;
    }
    __syncthreads();
    for (int i = t; i < 4096; i += 256) {
        int y = i >> 6;
        float mx = -INFINITY, sm = 0.0f;
#pragma unroll
        for (int dy = -2; dy <= 2; ++dy) {
            int yy = y + dy;
            if (0 <= yy && yy < 64) { mx = fmaxf(mx, hm[i + dy * 64]); sm += hs[i + dy * 64]; }
        }
        out[base + i] = f2bf(0.9f * mx + 0.1f * (sm * (1.0f / 25.0f)));
    }
}

// ---------------- fused separable 5x5 RW pool, bf16 io (global shift cancels)
__global__ __launch_bounds__(256)
void pool_rw_b(const unsigned short* __restrict__ in, unsigned short* __restrict__ out)
{
    __shared__ float xs[4096], hx[4096], he[4096];
    const size_t base = (size_t)blockIdx.x * 4096;
    const int t = threadIdx.x;
    for (int i = t; i < 4096; i += 256) xs[i] = bf2f(in[base + i]);
    __syncthreads();
    for (int i = t; i < 4096; i += 256) {
        int x = i & 63;
        float se = 0.0f, sx = 0.0f;
#pragma unroll
        for (int dx = -2; dx <= 2; ++dx) {
            int xx = x + dx;
            if (0 <= xx && xx < 64) {
                float v = xs[i + dx];
                float e = expf(v);
                se += e; sx += e * v;
            }
        }
        hx[i] = sx; he[i] = se;
    }
    __syncthreads();
    for (int i = t; i < 4096; i += 256) {
        int y = i >> 6;
        float se = 0.0f, sx = 0.0f;
#pragma unroll
        for (int dy = -2; dy <= 2; ++dy) {
            int yy = y + dy;
            if (0 <= yy && yy < 64) { sx += hx[i + dy * 64]; se += he[i + dy * 64]; }
        }
        out[base + i] = f2bf(sx / (se + 1e-6f));
    }
}

// ---------------- fused LSKA depthwise chain for a batch-QUAD, bf16 io
__global__ __launch_bounds__(256)
void lska_dw_quad(const unsigned short* __restrict__ Y2b, int b0,
                  const float* __restrict__ wh1, const float* __restrict__ bh1,
                  const float* __restrict__ wv1, const float* __restrict__ bv1,
                  const float* __restrict__ wh2, const float* __restrict__ bh2,
                  const float* __restrict__ wv2, const float* __restrict__ bv2,
                  unsigned short* __restrict__ outq)
{
    __shared__ float buf0[4096], buf1[4096];
    const int bi = blockIdx.x;
    const int zz = bi >> 10, c = bi & 1023;
    const unsigned short* src = Y2b + ((size_t)(b0 + zz) * 1024 + c) * 4096;
    unsigned short* dst = outq + (size_t)bi * 4096;
    const int t = threadIdx.x;
    for (int i = t; i < 4096; i += 256) buf0[i] = bf2f(src[i]);
    __syncthreads();
    {
        float w0 = wh1[c * 3], w1 = wh1[c * 3 + 1], w2 = wh1[c * 3 + 2], bb = bh1[c];
        for (int i = t; i < 4096; i += 256) {
            int x = i & 63;
            float a = fmaf(w1, buf0[i], bb);
            if (x >= 1)  a = fmaf(w0, buf0[i - 1], a);
            if (x <= 62) a = fmaf(w2, buf0[i + 1], a);
            buf1[i] = a;
        }
    }
    __syncthreads();
    {
        float w0 = wv1[c * 3], w1 = wv1[c * 3 + 1], w2 = wv1[c * 3 + 2], bb = bv1[c];
        for (int i = t; i < 4096; i += 256) {
            int y = i >> 6;
            float a = fmaf(w1, buf1[i], bb);
            if (y >= 1)  a = fmaf(w0, buf1[i - 64], a);
            if (y <= 62) a = fmaf(w2, buf1[i + 64], a);
            buf0[i] = a;
        }
    }
    __syncthreads();
    {
        float w0 = wh2[c * 3], w1 = wh2[c * 3 + 1], w2 = wh2[c * 3 + 2], bb = bh2[c];
        for (int i = t; i < 4096; i += 256) {
            int x = i & 63;
            float a = fmaf(w1, buf0[i], bb);
            if (x >= 2)  a = fmaf(w0, buf0[i - 2], a);
            if (x <= 61) a = fmaf(w2, buf0[i + 2], a);
            buf1[i] = a;
        }
    }
    __syncthreads();
    {
        float w0 = wv2[c * 3], w1 = wv2[c * 3 + 1], w2 = wv2[c * 3 + 2], bb = bv2[c];
        for (int i = t; i < 4096; i += 256) {
            int y = i >> 6;
            float a = fmaf(w1, buf1[i], bb);
            if (y >= 2)  a = fmaf(w0, buf1[i - 128], a);
            if (y <= 61) a = fmaf(w2, buf1[i + 128], a);
            dst[i] = f2bf(a);
        }
    }
}

// ---------------- conversions
__global__ void f2bf_vec(const float* __restrict__ in, unsigned short* __restrict__ out)
{
    size_t i = ((size_t)blockIdx.x * 256 + threadIdx.x) * 8;
    float4 v0 = *(const float4*)(in + i);
    float4 v1 = *(const float4*)(in + i + 4);
    uint2 o0, o1;
    o0.x = (unsigned)f2bf(v0.x) | ((unsigned)f2bf(v0.y) << 16);
    o0.y = (unsigned)f2bf(v0.z) | ((unsigned)f2bf(v0.w) << 16);
    o1.x = (unsigned)f2bf(v1.x) | ((unsigned)f2bf(v1.y) << 16);
    o1.y = (unsigned)f2bf(v1.z) | ((unsigned)f2bf(v1.w) << 16);
    *(uint2*)(out + i) = o0;
    *(uint2*)(out + i + 4) = o1;
}

__global__ void whi(const float* __restrict__ w, unsigned short* __restrict__ wh)
{
    int i = blockIdx.x * 256 + threadIdx.x;
    wh[i] = f2bf(w[i]);
}

extern "C" void kernel_launch(void* const* d_in, const int* in_sizes, int n_in,
                              void* d_out, int out_size, void* d_ws, size_t ws_size,
                              hipStream_t stream)
{
    const float* x       = (const float*)d_in[0];
    const float* w_sta   = (const float*)d_in[1];
    const float* b_sta   = (const float*)d_in[2];
    const float* w_cv1   = (const float*)d_in[3];
    const float* b_cv1   = (const float*)d_in[4];
    const float* w_cv2   = (const float*)d_in[5];
    const float* b_cv2   = (const float*)d_in[6];
    const float* w_cvend = (const float*)d_in[7];
    const float* b_cvend = (const float*)d_in[8];
    const float* w_dwh   = (const float*)d_in[9];
    const float* b_dwh   = (const float*)d_in[10];
    const float* w_dwv   = (const float*)d_in[11];
    const float* b_dwv   = (const float*)d_in[12];
    const float* w_ddwh  = (const float*)d_in[13];
    const float* b_ddwh  = (const float*)d_in[14];
    const float* w_ddwv  = (const float*)d_in[15];
    const float* b_ddwv  = (const float*)d_in[16];
    const float* w_c1    = (const float*)d_in[17];
    const float* b_c1    = (const float*)d_in[18];
    float* outf = (float*)d_out;
    unsigned short* Y2b = (unsigned short*)d_out;   // [8,1024,4096] bf16 = 67.1 MB

    // ws (bf16 element offsets), total 122.9 MB <= 128 MiB. Overlays: xb = t1+t2
    // (dead until pools run); phase-5: a4q = xaux+t1, gq = t2+t3.
    unsigned short* WS   = (unsigned short*)d_ws;
    unsigned short* xaux = WS;
    unsigned short* t1   = WS + 8388608;
    unsigned short* t2   = WS + 16777216;
    unsigned short* t3   = WS + 25165824;
    unsigned short* r1   = WS + 33554432;
    unsigned short* r2   = WS + 41943040;
    unsigned short* r3   = WS + 50331648;
    unsigned short* WT   = WS + 58720256;
    unsigned short* xb   = t1;
    unsigned short* a4q  = WS;
    unsigned short* gq   = WS + 16777216;

    unsigned short* sta_h = WT;              // 131072
    unsigned short* cv1_h = WT + 131072;     // 524288
    unsigned short* cv2_h = WT + 655360;     // 524288
    unsigned short* c1_h  = WT + 1179648;    // 1048576
    unsigned short* cve_h = WT + 2228224;    // 524288

    dim3 blk(256);

    // 0) conversions
    f2bf_vec<<<8192, blk, 0, stream>>>(x, xb);
    whi<<<512,  blk, 0, stream>>>(w_sta,   sta_h);
    whi<<<2048, blk, 0, stream>>>(w_cv1,   cv1_h);
    whi<<<2048, blk, 0, stream>>>(w_cv2,   cv2_h);
    whi<<<4096, blk, 0, stream>>>(w_c1,    c1_h);
    whi<<<2048, blk, 0, stream>>>(w_cvend, cve_h);

    // 1) x_aux = SiLU(sta(x)) -> bf16 [8,256,4096]
    {
        BSlots s; s.p[0] = xb; s.p[1] = xb + 1048576; s.p[2] = xb; s.p[3] = xb;
        gemm_mfma<0><<<dim3(32, 2, 8), blk, 0, stream>>>(
            sta_h, nullptr, 512, s, s, 2097152L, b_sta, nullptr,
            xaux, 256, nullptr, 0, 512);
    }

    // 2) RW pool cascade -> r1,r2,r3
    pool_rw_b<<<2048, blk, 0, stream>>>(xaux, r1);
    pool_rw_b<<<2048, blk, 0, stream>>>(r1, r2);
    pool_rw_b<<<2048, blk, 0, stream>>>(r2, r3);

    // 3) TMaxAvg cascade -> t1,t2,t3 (t1 overwrites xb, which is dead)
    pool_tma_b<<<2048, blk, 0, stream>>>(xaux, t1);
    pool_tma_b<<<2048, blk, 0, stream>>>(t1, t2);
    pool_tma_b<<<2048, blk, 0, stream>>>(t2, t3);

    // 4) merged cv1+cv2 -> Y2b channels [0,512)=cv1, [512,1024)=cv2
    {
        BSlots s1; s1.p[0] = xaux; s1.p[1] = t1; s1.p[2] = t2; s1.p[3] = t3;
        BSlots s2; s2.p[0] = xaux; s2.p[1] = r1; s2.p[2] = r2; s2.p[3] = r3;
        gemm_mfma<0><<<dim3(32, 8, 8), blk, 0, stream>>>(
            cv1_h, cv2_h, 1024, s1, s2, 1048576L, b_cv1, b_cv2,
            Y2b, 1024, nullptr, 0, 1024);
    }

    // 5) per batch-quad: dw chain -> a4q ; gated c1 -> gq ; cvend -> d_out
    for (int qd = 0; qd < 2; ++qd) {
        const int b0 = 4 * qd;
        lska_dw_quad<<<4096, blk, 0, stream>>>(Y2b, b0,
                                               w_dwh, b_dwh, w_dwv, b_dwv,
                                               w_ddwh, b_ddwh, w_ddwv, b_ddwv, a4q);
        {
            BSlots s; s.p[0] = a4q; s.p[1] = a4q + 1048576;
            s.p[2] = a4q + 2097152; s.p[3] = a4q + 3145728;
            gemm_mfma<1><<<dim3(32, 8, 4), blk, 0, stream>>>(
                c1_h, nullptr, 1024, s, s, 4194304L, b_c1, nullptr,
                gq, 1024, Y2b, b0, 1024);
        }
        {
            BSlots s; s.p[0] = gq; s.p[1] = gq + 1048576;
            s.p[2] = gq + 2097152; s.p[3] = gq + 3145728;
            gemm_mfma<2><<<dim3(32, 4, 4), blk, 0, stream>>>(
                cve_h, nullptr, 1024, s, s, 4194304L, b_cvend, nullptr,
                outf + (size_t)b0 * 2097152, 512, nullptr, 0, 1024);
        }
    }
}